// Round 2
// baseline (252.315 us; speedup 1.0000x reference)
//
#include <hip/hip_runtime.h>

#define B_ 64
#define C_ 3
#define H_ 384
#define W_ 384
#define HW_ (H_ * W_)

// 2 output pixels (same row, x and x+1) per thread.
__global__ __launch_bounds__(256) void affine_sample_kernel(
    const float* __restrict__ imgs,
    const float* __restrict__ theta,
    float* __restrict__ out)
{
    // XCD swizzle: consecutive blockIdx are dealt round-robin across 8 XCDs.
    // Remap so each XCD gets a contiguous pixel range -> y-adjacent output
    // rows (which share source rows) hit the same XCD L2.
    int nb = gridDim.x;              // multiple of 8
    int chunk = nb >> 3;
    int bid = blockIdx.x;
    int sb = (bid & 7) * chunk + (bid >> 3);

    int idx = sb * 256 + threadIdx.x;
    int px = idx * 2;                // first of 2 consecutive x pixels
    int x = px % W_;                 // W even -> both pixels in same row
    int t = px / W_;
    int y = t % H_;
    int b = t / H_;
    b = __builtin_amdgcn_readfirstlane(b);   // block-uniform (576/288 blocks per image exactly)

    const float* th = theta + b * 6;
    float t00 = th[0], t01 = th[1], t02 = th[2];
    float t10 = th[3], t11 = th[4], t12 = th[5];

    float yg = (float)y - 191.5f;
    float iy_base = fmaf(yg, t01, t02) + 191.5f;   // x-part added per pixel
    float ix_base_y = fmaf(yg, t11, t12) + 191.5f;

    const float* bimg = imgs + (size_t)b * (C_ * HW_);
    float* bout = out + (size_t)b * (C_ * HW_) + y * W_ + x;

    float res[2][C_];
    int offs[2][4];
    float wts[2][4];

#pragma unroll
    for (int j = 0; j < 2; ++j) {
        float xg = (float)(x + j) - 191.5f;
        float ix = fmaf(xg, t00, iy_base);
        float iy = fmaf(xg, t10, ix_base_y);

        float x0f = floorf(ix);
        float y0f = floorf(iy);
        float wx1 = ix - x0f;
        float wy1 = iy - y0f;
        float wx0 = 1.0f - wx1;
        float wy0 = 1.0f - wy1;
        float x1f = x0f + 1.0f;
        float y1f = y0f + 1.0f;

        bool vx0 = (x0f >= 0.0f) && (x0f < (float)W_);
        bool vx1 = (x1f >= 0.0f) && (x1f < (float)W_);
        bool vy0 = (y0f >= 0.0f) && (y0f < (float)H_);
        bool vy1 = (y1f >= 0.0f) && (y1f < (float)H_);

        int x0 = (int)fminf(fmaxf(x0f, 0.0f), (float)(W_ - 1));
        int x1 = (int)fminf(fmaxf(x1f, 0.0f), (float)(W_ - 1));
        int y0 = (int)fminf(fmaxf(y0f, 0.0f), (float)(H_ - 1));
        int y1 = (int)fminf(fmaxf(y1f, 0.0f), (float)(H_ - 1));

        wts[j][0] = wx0 * wy0 * ((vx0 && vy0) ? 1.0f : 0.0f);
        wts[j][1] = wx1 * wy0 * ((vx1 && vy0) ? 1.0f : 0.0f);
        wts[j][2] = wx0 * wy1 * ((vx0 && vy1) ? 1.0f : 0.0f);
        wts[j][3] = wx1 * wy1 * ((vx1 && vy1) ? 1.0f : 0.0f);

        offs[j][0] = y0 * W_ + x0;
        offs[j][1] = y0 * W_ + x1;
        offs[j][2] = y1 * W_ + x0;
        offs[j][3] = y1 * W_ + x1;
    }

#pragma unroll
    for (int c = 0; c < C_; ++c) {
        const float* p = bimg + c * HW_;
#pragma unroll
        for (int j = 0; j < 2; ++j) {
            float v00 = p[offs[j][0]];
            float v01 = p[offs[j][1]];
            float v10 = p[offs[j][2]];
            float v11 = p[offs[j][3]];
            res[j][c] = fmaf(v00, wts[j][0],
                        fmaf(v01, wts[j][1],
                        fmaf(v10, wts[j][2], v11 * wts[j][3])));
        }
    }

#pragma unroll
    for (int c = 0; c < C_; ++c) {
        float2 r = make_float2(res[0][c], res[1][c]);
        *(float2*)(bout + c * HW_) = r;   // x even, base 8B-aligned
    }
}

extern "C" void kernel_launch(void* const* d_in, const int* in_sizes, int n_in,
                              void* d_out, int out_size, void* d_ws, size_t ws_size,
                              hipStream_t stream) {
    const float* imgs = (const float*)d_in[0];
    const float* theta = (const float*)d_in[1];
    float* out = (float*)d_out;
    int total_threads = B_ * H_ * W_ / 2;     // 4,718,592
    int blocks = total_threads / 256;         // 18,432 (multiple of 8)
    affine_sample_kernel<<<blocks, 256, 0, stream>>>(imgs, theta, out);
}